// Round 13
// baseline (171.961 us; speedup 1.0000x reference)
//
#include <hip/hip_runtime.h>
#include <math.h>

// ---------------------------------------------------------------------------
// TransformerBlock: B=2, S=2048, D=512, H=8, HD=64, DFF=2048, fp32 in/out.
// bf16 MFMA 16x16x32. Verified layouts:
//   A-frag:  A[m = lane&15][k = (lane>>4)*8 + j]
//   B-frag:  B[n = lane&15][k = (lane>>4)*8 + j]   (W[N][K] row-major)
//   C/D:     col = lane&15, row = (lane>>4)*4 + reg
// Round 13 = round 12 (best, 168.1) + qkv TN=64 (1536 blocks ~6/CU) +
// MLP1 TM=32 (2048 blocks = 8/CU). rmsnorm2 eliminated algebraically
// (n2s folded into W1; rms scale applied in MLP1 epilogue from rssum).
// MLP2 split-K=2 atomics into out preinit'd by outproj epilogue.
// Attention ALiBi-windowed (dist <= 16(h+1)+16), m=0 streaming softmax,
// l via ones-MFMA. V key-permuted in 32-groups: c' = 2*(g&15) + (g>>4).
// ---------------------------------------------------------------------------

typedef __bf16 bf16x8 __attribute__((ext_vector_type(8)));
typedef float  f32x4  __attribute__((ext_vector_type(4)));

#define TOKENS 4096
#define DMODEL 512
#define SEQ    2048
#define QSCALE 0.1803368801f   // 0.125 * log2(e)

__device__ __forceinline__ void gl_lds16(const __bf16* g, __bf16* l) {
    __builtin_amdgcn_global_load_lds(
        (const __attribute__((address_space(1))) void*)g,
        (__attribute__((address_space(3))) void*)l, 16, 0, 0);
}

union PkU { unsigned u; __bf16 h[2]; };

// ------- fused: rmsnorm1 (0..1023) + 4 weight converts (1024..4095, n2s
// folded into W1) + rssum zero (block 4096) --------------------------------
__global__ void pre_kernel(const float* __restrict__ x, const float* __restrict__ n1s,
                           const float* __restrict__ n2s, __bf16* __restrict__ xn1,
                           const float* __restrict__ wa, const float* __restrict__ wb,
                           const float* __restrict__ wc, const float* __restrict__ wd,
                           __bf16* __restrict__ da, __bf16* __restrict__ db,
                           __bf16* __restrict__ dc, __bf16* __restrict__ dd,
                           float* __restrict__ rssum) {
    if (blockIdx.x < 1024) {
        int wave = threadIdx.x >> 6, lane = threadIdx.x & 63;
        int tok = blockIdx.x * 4 + wave;
        const float* row = x + (size_t)tok * DMODEL;
        float4 v0 = *(const float4*)&row[lane * 4];
        float4 v1 = *(const float4*)&row[256 + lane * 4];
        float ss = v0.x*v0.x + v0.y*v0.y + v0.z*v0.z + v0.w*v0.w
                 + v1.x*v1.x + v1.y*v1.y + v1.z*v1.z + v1.w*v1.w;
        #pragma unroll
        for (int off = 1; off < 64; off <<= 1) ss += __shfl_xor(ss, off);
        float r = rsqrtf(ss * (1.0f / DMODEL) + 1e-8f);
        __bf16* o = xn1 + (size_t)tok * DMODEL;
        o[lane*4 + 0] = (__bf16)(v0.x * r * n1s[lane*4 + 0]);
        o[lane*4 + 1] = (__bf16)(v0.y * r * n1s[lane*4 + 1]);
        o[lane*4 + 2] = (__bf16)(v0.z * r * n1s[lane*4 + 2]);
        o[lane*4 + 3] = (__bf16)(v0.w * r * n1s[lane*4 + 3]);
        o[256 + lane*4 + 0] = (__bf16)(v1.x * r * n1s[256 + lane*4 + 0]);
        o[256 + lane*4 + 1] = (__bf16)(v1.y * r * n1s[256 + lane*4 + 1]);
        o[256 + lane*4 + 2] = (__bf16)(v1.z * r * n1s[256 + lane*4 + 2]);
        o[256 + lane*4 + 3] = (__bf16)(v1.w * r * n1s[256 + lane*4 + 3]);
    } else if (blockIdx.x < 4096) {
        const int N0 = 1536 * 512, N1 = 512 * 512, N2 = 2048 * 512, N3 = 512 * 2048;
        int i4 = ((blockIdx.x - 1024) * 256 + threadIdx.x) * 4;
        if (i4 < N0) {
            float4 v = *(const float4*)&wa[i4];
            __bf16* d = da + i4;
            d[0] = (__bf16)v.x; d[1] = (__bf16)v.y; d[2] = (__bf16)v.z; d[3] = (__bf16)v.w;
        } else if ((i4 -= N0) < N1) {
            float4 v = *(const float4*)&wb[i4];
            __bf16* d = db + i4;
            d[0] = (__bf16)v.x; d[1] = (__bf16)v.y; d[2] = (__bf16)v.z; d[3] = (__bf16)v.w;
        } else if ((i4 -= N1) < N2) {
            float4 v = *(const float4*)&wc[i4];
            float4 sc = *(const float4*)&n2s[i4 & 511];   // fold n2s into W1
            __bf16* d = dc + i4;
            d[0] = (__bf16)(v.x * sc.x); d[1] = (__bf16)(v.y * sc.y);
            d[2] = (__bf16)(v.z * sc.z); d[3] = (__bf16)(v.w * sc.w);
        } else if ((i4 -= N2) < N3) {
            float4 v = *(const float4*)&wd[i4];
            __bf16* d = dd + i4;
            d[0] = (__bf16)v.x; d[1] = (__bf16)v.y; d[2] = (__bf16)v.z; d[3] = (__bf16)v.w;
        }
    } else {
        float4 z = make_float4(0.f, 0.f, 0.f, 0.f);
        int i = threadIdx.x * 16;
        *(float4*)&rssum[i + 0]  = z;
        *(float4*)&rssum[i + 4]  = z;
        *(float4*)&rssum[i + 8]  = z;
        *(float4*)&rssum[i + 12] = z;
    }
}

// ---------------- GEMM: C[M,N] = A[M,K] @ W[N,K]^T (+ bias) ----------------
// EPI: 4 = qkv split: Q*QSCALE -> qb, K -> kb, V -> vtb (key-permuted pack)
//      5 = fp32 unsafeAtomicAdd into Cf (no bias; split-K via blockIdx.z)
//      8 = x1 = res + C + bias: Cb=bf16 x1, Cf = x1 + b2x (out preinit),
//          atomicAdd per-row sum-of-squares into rssum
//      9 = bf16 tanh-gelu(C * rms[row] + bias), rms from rssum (MLP1)
template <int EPI, int TM, int TN, int KS = 1>
__global__ __launch_bounds__(256) void gemm_bt(
    const __bf16* __restrict__ A, const __bf16* __restrict__ W,
    const float* __restrict__ bias, const float* __restrict__ res,
    float* __restrict__ Cf, __bf16* __restrict__ Cb,
    __bf16* __restrict__ qb, __bf16* __restrict__ kb, __bf16* __restrict__ vtb,
    const float* __restrict__ b2x, float* __restrict__ rssum,
    int M, int N, int K)
{
    constexpr int RI = TM / 32;
    constexpr int NJ = TN / 32;
    __shared__ alignas(16) __bf16 As[2][TM * 32];
    __shared__ alignas(16) __bf16 Bs[2][TN * 32];
    const int tid = threadIdx.x;
    const int bm = blockIdx.x * TM;
    const int bn = blockIdx.y * TN;
    const int wave = tid >> 6, lane = tid & 63;
    const int wm = (wave & 1) * (TM / 2), wn = (wave >> 1) * (TN / 2);
    const int lrow = lane & 15;
    const int kq = (lane >> 4) * 8;

    f32x4 acc[RI][NJ] = {};

    const int Kc = K / KS;
    const int kbeg = (KS > 1) ? blockIdx.z * Kc : 0;

    for (int k0 = kbeg; k0 < kbeg + Kc; k0 += 64) {
        __syncthreads();
        #pragma unroll
        for (int i = 0; i < TM / 32; i++) {
            int tt = i * 256 + tid;
            int kh = tt / (TM * 4), rem = tt % (TM * 4);
            int mrow = rem >> 2, c8 = rem & 3;
            gl_lds16(&A[(size_t)(bm + mrow) * K + k0 + kh * 32 + c8 * 8],
                     (__bf16*)As + tt * 8);
        }
        #pragma unroll
        for (int i = 0; i < TN / 32; i++) {
            int tt = i * 256 + tid;
            int kh = tt / (TN * 4), rem = tt % (TN * 4);
            int nrow = rem >> 2, c8 = rem & 3;
            gl_lds16(&W[(size_t)(bn + nrow) * K + k0 + kh * 32 + c8 * 8],
                     (__bf16*)Bs + tt * 8);
        }
        __syncthreads();
        #pragma unroll
        for (int kh = 0; kh < 2; kh++) {
            bf16x8 af[RI], bfv[NJ];
            #pragma unroll
            for (int i = 0; i < RI; i++) af[i] = *(bf16x8*)&As[kh][(wm + i*16 + lrow)*32 + kq];
            #pragma unroll
            for (int j = 0; j < NJ; j++) bfv[j] = *(bf16x8*)&Bs[kh][(wn + j*16 + lrow)*32 + kq];
            #pragma unroll
            for (int i = 0; i < RI; i++)
                #pragma unroll
                for (int j = 0; j < NJ; j++)
                    acc[i][j] = __builtin_amdgcn_mfma_f32_16x16x32_bf16(af[i], bfv[j], acc[i][j], 0, 0, 0);
        }
    }

    const int crow0 = (lane >> 4) * 4;
    const int ccol = lane & 15;
    const int quad = lane >> 4;

    if (EPI == 4) {
        #pragma unroll
        for (int j = 0; j < NJ; j++) {
            const int col = bn + wn + j * 16 + ccol;
            const float bv = bias[col];
            if (col < 512) {
                const int h = col >> 6, d = col & 63;
                #pragma unroll
                for (int i = 0; i < RI; i++) {
                    const int row0 = bm + wm + i * 16 + crow0;
                    const int b = row0 >> 11, s0 = row0 & 2047;
                    #pragma unroll
                    for (int r = 0; r < 4; r++)
                        qb[(((size_t)b*8 + h)*2048 + s0 + r)*64 + d] =
                            (__bf16)((acc[i][j][r] + bv) * QSCALE);
                }
            } else if (col < 1024) {
                const int h = (col - 512) >> 6, d = col & 63;
                #pragma unroll
                for (int i = 0; i < RI; i++) {
                    const int row0 = bm + wm + i * 16 + crow0;
                    const int b = row0 >> 11, s0 = row0 & 2047;
                    #pragma unroll
                    for (int r = 0; r < 4; r++)
                        kb[(((size_t)b*8 + h)*2048 + s0 + r)*64 + d] = (__bf16)(acc[i][j][r] + bv);
                }
            } else {
                const int h = (col - 1024) >> 6, d = col & 63;
                const int tok0 = bm + wm;            // 32-aligned
                const int b = tok0 >> 11, sbase = tok0 & 2047;
                unsigned* vrow = (unsigned*)vtb + (((size_t)b*8 + h)*64 + d) * 1024 + (sbase >> 1);
                #pragma unroll
                for (int ip = 0; ip < RI / 2; ip++) {
                    #pragma unroll
                    for (int r = 0; r < 4; r++) {
                        PkU pk;                      // c' = 2*(g&15) + (g>>4)
                        pk.h[0] = (__bf16)(acc[2*ip][j][r] + bv);
                        pk.h[1] = (__bf16)(acc[2*ip+1][j][r] + bv);
                        vrow[ip * 16 + quad * 4 + r] = pk.u;
                    }
                }
            }
        }
    } else {
        #pragma unroll
        for (int i = 0; i < RI; i++) {
            const int row0 = bm + wm + i * 16 + crow0;
            if (EPI == 9) {
                float rms[4];
                #pragma unroll
                for (int r = 0; r < 4; r++)
                    rms[r] = rsqrtf(rssum[row0 + r] * (1.0f / 512.0f) + 1e-8f);
                #pragma unroll
                for (int j = 0; j < NJ; j++) {
                    const int col = bn + wn + j * 16 + ccol;
                    const float bv = bias[col];
                    #pragma unroll
                    for (int r = 0; r < 4; r++) {
                        float v = acc[i][j][r] * rms[r] + bv;
                        float u = v * (0.7978845608f + 0.0356774081f * v * v);
                        float t = exp2f(u * 2.8853900818f);
                        Cb[(size_t)(row0 + r) * N + col] = (__bf16)(v - v / (t + 1.0f));
                    }
                }
            } else if (EPI == 8) {
                float ssq[4] = {};
                #pragma unroll
                for (int j = 0; j < NJ; j++) {
                    const int col = bn + wn + j * 16 + ccol;
                    const float bv = bias[col], b2v = b2x[col];
                    #pragma unroll
                    for (int r = 0; r < 4; r++) {
                        const size_t idx = (size_t)(row0 + r) * N + col;
                        float v = res[idx] + acc[i][j][r] + bv;
                        Cb[idx] = (__bf16)v;          // x1 bf16
                        Cf[idx] = v + b2v;            // out preinit
                        ssq[r] += v * v;
                    }
                }
                #pragma unroll
                for (int r = 0; r < 4; r++) {
                    #pragma unroll
                    for (int off = 1; off < 16; off <<= 1)
                        ssq[r] += __shfl_xor(ssq[r], off);
                }
                if (ccol == 0) {
                    #pragma unroll
                    for (int r = 0; r < 4; r++)
                        unsafeAtomicAdd(&rssum[row0 + r], ssq[r]);
                }
            } else { // EPI == 5
                #pragma unroll
                for (int j = 0; j < NJ; j++) {
                    const int col = bn + wn + j * 16 + ccol;
                    #pragma unroll
                    for (int r = 0; r < 4; r++)
                        unsafeAtomicAdd(&Cf[(size_t)(row0 + r) * N + col], acc[i][j][r]);
                }
            }
        }
    }
}

// ---------------- ALiBi-windowed flash attention ----------------------------
__global__ __launch_bounds__(256) void attn_kernel(
    const __bf16* __restrict__ qb, const __bf16* __restrict__ kb,
    const __bf16* __restrict__ vtb, __bf16* __restrict__ ctx)
{
    const int id = blockIdx.x;
    const int qt = id >> 4;
    const int bh = (id & 15) ^ (7 * (id >> 8));
    const int h = bh & 7, b = bh >> 3;
    const int tid = threadIdx.x, wave = tid >> 6, lane = tid & 63;
    const int lrow = lane & 15, quad = lane >> 4;

    __shared__ alignas(16) __bf16 Ks[2][2][64 * 32];
    __shared__ alignas(16) __bf16 Vt[2][2][64 * 32];
    __shared__ alignas(16) unsigned Pt4[4][2][16][20];

    const float slope2 = -1.44269504f / (float)(h + 1);
    const int q0 = qt * 64;
    const int D = 16 * (h + 1) + 16;
    const int kt_lo = max(0, q0 - D) >> 6;
    const int kt_hi = min(SEQ - 1, q0 + 63 + D) >> 6;

    bf16x8 qf[2];
    #pragma unroll
    for (int dh = 0; dh < 2; dh++)
        qf[dh] = *(const bf16x8*)&qb[((size_t)bh*2048 + q0 + wave*16 + lrow)*64 + dh*32 + quad*8];

    bf16x8 ones;
    #pragma unroll
    for (int j = 0; j < 8; j++) ones[j] = (__bf16)1.0f;

    f32x4 O[4] = {};
    f32x4 lacc = {};

    auto stage = [&](int kt, int buf) {
        const int kbase = kt * 64;
        #pragma unroll
        for (int i = 0; i < 2; i++) {
            int tt = i * 256 + tid;
            int dh = tt >> 8, key = (tt & 255) >> 2, c8 = (tt & 3) * 8;
            gl_lds16(&kb[((size_t)bh*2048 + kbase + key)*64 + dh*32 + c8],
                     (__bf16*)Ks[buf] + tt * 8);
        }
        #pragma unroll
        for (int i = 0; i < 2; i++) {
            int tt = i * 256 + tid;
            int kh = tt >> 8, d = (tt & 255) >> 2, ck = (tt & 3) * 8;
            gl_lds16(&vtb[((size_t)bh*64 + d)*2048 + kbase + kh*32 + ck],
                     (__bf16*)Vt[buf] + tt * 8);
        }
    };

    stage(kt_lo, 0);

    for (int kt = kt_lo, buf = 0; kt <= kt_hi; kt++, buf ^= 1) {
        __syncthreads();
        if (kt < kt_hi) stage(kt + 1, buf ^ 1);

        bf16x8 kf[4][2];
        #pragma unroll
        for (int j = 0; j < 4; j++)
            #pragma unroll
            for (int dh = 0; dh < 2; dh++)
                kf[j][dh] = *(bf16x8*)&Ks[buf][dh][(j*16 + lrow)*32 + quad*8];

        f32x4 Sc[4] = {};
        #pragma unroll
        for (int dh = 0; dh < 2; dh++)
            #pragma unroll
            for (int j = 0; j < 4; j++)
                Sc[j] = __builtin_amdgcn_mfma_f32_16x16x32_bf16(qf[dh], kf[j][dh], Sc[j], 0, 0, 0);

        const float dbase = (float)(q0 + wave*16 + quad*4 - kt*64 - lrow);
        #pragma unroll
        for (int r = 0; r < 4; r++) {
            const float d0 = dbase + (float)r;
            #pragma unroll
            for (int jp = 0; jp < 2; jp++) {
                float v0 = fmaf(slope2, fabsf(d0 - (float)(jp*32)),      Sc[2*jp  ][r]);
                float v1 = fmaf(slope2, fabsf(d0 - (float)(jp*32 + 16)), Sc[2*jp+1][r]);
                PkU pk;
                pk.h[0] = (__bf16)exp2f(v0);
                pk.h[1] = (__bf16)exp2f(v1);
                Pt4[wave][jp][quad*4 + r][lrow] = pk.u;
            }
        }

        bf16x8 pf[2];
        #pragma unroll
        for (int kh = 0; kh < 2; kh++)
            pf[kh] = *(bf16x8*)&Pt4[wave][kh][lrow][quad*4];

        #pragma unroll
        for (int kh = 0; kh < 2; kh++)
            lacc = __builtin_amdgcn_mfma_f32_16x16x32_bf16(pf[kh], ones, lacc, 0, 0, 0);

        #pragma unroll
        for (int dt = 0; dt < 4; dt++) {
            #pragma unroll
            for (int kh = 0; kh < 2; kh++) {
                bf16x8 vf = *(bf16x8*)&Vt[buf][kh][(dt*16 + lrow)*32 + quad*8];
                O[dt] = __builtin_amdgcn_mfma_f32_16x16x32_bf16(pf[kh], vf, O[dt], 0, 0, 0);
            }
        }
    }

    #pragma unroll
    for (int dt = 0; dt < 4; dt++) {
        #pragma unroll
        for (int r = 0; r < 4; r++) {
            const int q = q0 + wave*16 + quad*4 + r;
            ctx[((size_t)(b * 2048 + q)) * DMODEL + h * 64 + dt*16 + lrow] =
                (__bf16)(O[dt][r] / lacc[r]);
        }
    }
}

// ---------------------------------------------------------------------------
extern "C" void kernel_launch(void* const* d_in, const int* in_sizes, int n_in,
                              void* d_out, int out_size, void* d_ws, size_t ws_size,
                              hipStream_t stream) {
    const float* x    = (const float*)d_in[0];
    const float* n1s  = (const float*)d_in[1];
    const float* n2s  = (const float*)d_in[2];
    const float* wqkv = (const float*)d_in[3];
    const float* bqkv = (const float*)d_in[4];
    const float* wout = (const float*)d_in[5];
    const float* bout = (const float*)d_in[6];
    const float* w1   = (const float*)d_in[7];
    const float* b1   = (const float*)d_in[8];
    const float* w2   = (const float*)d_in[9];
    const float* b2   = (const float*)d_in[10];
    float* out = (float*)d_out;

    char* ws = (char*)d_ws;
    __bf16* xn1     = (__bf16*)ws; ws += (size_t)TOKENS * DMODEL * 2;
    __bf16* qbuf    = (__bf16*)ws; ws += (size_t)TOKENS * DMODEL * 2;
    __bf16* kbuf    = (__bf16*)ws; ws += (size_t)TOKENS * DMODEL * 2;
    __bf16* vtbuf   = (__bf16*)ws; ws += (size_t)TOKENS * DMODEL * 2;
    __bf16* wqkv_b  = (__bf16*)ws; ws += (size_t)1536 * DMODEL * 2;
    __bf16* wout_b  = (__bf16*)ws; ws += (size_t)DMODEL * DMODEL * 2;
    __bf16* w1n_b   = (__bf16*)ws; ws += (size_t)2048 * DMODEL * 2;
    __bf16* w2_b    = (__bf16*)ws; ws += (size_t)DMODEL * 2048 * 2;
    __bf16* ctx     = (__bf16*)ws; ws += (size_t)TOKENS * DMODEL * 2;
    __bf16* x1b     = (__bf16*)ws; ws += (size_t)TOKENS * DMODEL * 2;
    __bf16* hbuf    = (__bf16*)ws; ws += (size_t)TOKENS * 2048 * 2;
    float*  rssum   = (float*)ws;  ws += (size_t)TOKENS * 4;

    // 1) rmsnorm1 + weight converts (n2s folded into W1) + rssum zero
    pre_kernel<<<dim3(4097), 256, 0, stream>>>(x, n1s, n2s, xn1,
        wqkv, wout, w1, w2, wqkv_b, wout_b, w1n_b, w2_b, rssum);

    // 2) qkv GEMM (64x64 tiles, 1536 blocks ~6/CU) -> q (scaled), k, v-perm
    gemm_bt<4, 64, 64><<<dim3(TOKENS / 64, 1536 / 64), 256, 0, stream>>>(
        xn1, wqkv_b, bqkv, nullptr, nullptr, nullptr, qbuf, kbuf, vtbuf,
        nullptr, nullptr, TOKENS, 1536, DMODEL);

    // 3) windowed attention -> ctx (512 blocks)
    attn_kernel<<<dim3(512), 256, 0, stream>>>(qbuf, kbuf, vtbuf, ctx);

    // 4) x1 = x + ctx @ Wout^T + bout -> x1b (bf16); out = x1 + b2;
    //    rssum += per-row sum(x1^2)   (32x128 tiles, 512 blocks)
    gemm_bt<8, 32, 128><<<dim3(TOKENS / 32, DMODEL / 128), 256, 0, stream>>>(
        ctx, wout_b, bout, x, out, x1b, nullptr, nullptr, nullptr,
        b2, rssum, TOKENS, DMODEL, DMODEL);

    // 5) h = tanh-gelu(rms[row] * (x1b @ W1n^T) + b1)  (32x128, 2048 blocks)
    gemm_bt<9, 32, 128><<<dim3(TOKENS / 32, 2048 / 128), 256, 0, stream>>>(
        x1b, w1n_b, b1, nullptr, nullptr, hbuf, nullptr, nullptr, nullptr,
        nullptr, rssum, TOKENS, 2048, DMODEL);

    // 6) out += h @ W2^T  (split-K=2 atomics, 1024 blocks)
    gemm_bt<5, 32, 128, 2><<<dim3(TOKENS / 32, DMODEL / 128, 2), 256, 0, stream>>>(
        hbuf, w2_b, nullptr, nullptr, out, nullptr, nullptr, nullptr, nullptr,
        nullptr, nullptr, TOKENS, DMODEL, 2048);
}

// Round 14
// 167.261 us; speedup vs baseline: 1.0281x; 1.0281x over previous
//
#include <hip/hip_runtime.h>
#include <math.h>

// ---------------------------------------------------------------------------
// TransformerBlock: B=2, S=2048, D=512, H=8, HD=64, DFF=2048, fp32 in/out.
// bf16 MFMA 16x16x32. Verified layouts:
//   A-frag:  A[m = lane&15][k = (lane>>4)*8 + j]
//   B-frag:  B[n = lane&15][k = (lane>>4)*8 + j]   (W[N][K] row-major)
//   C/D:     col = lane&15, row = (lane>>4)*4 + reg
// Round 14 = round 12 verbatim (measured best, 168.1 us). r13's qkv TN=64 +
// MLP1 TM=32 regressed (172.0); tile space fully mapped, r12 is the optimum.
//   - rmsnorm2 eliminated algebraically: n2s folded into W1 convert;
//     rms scale applied in MLP1 epilogue from rssum (outproj epilogue atomics)
//   - MLP2 split-K=2 atomics into out preinit'd by outproj epilogue
//   - Attention ALiBi-windowed (dist <= 16(h+1)+16), m=0 streaming softmax,
//     l via ones-MFMA; V key-permuted in 32-groups: c' = 2*(g&15) + (g>>4)
// ---------------------------------------------------------------------------

typedef __bf16 bf16x8 __attribute__((ext_vector_type(8)));
typedef float  f32x4  __attribute__((ext_vector_type(4)));

#define TOKENS 4096
#define DMODEL 512
#define SEQ    2048
#define QSCALE 0.1803368801f   // 0.125 * log2(e)

__device__ __forceinline__ void gl_lds16(const __bf16* g, __bf16* l) {
    __builtin_amdgcn_global_load_lds(
        (const __attribute__((address_space(1))) void*)g,
        (__attribute__((address_space(3))) void*)l, 16, 0, 0);
}

union PkU { unsigned u; __bf16 h[2]; };

// ------- fused: rmsnorm1 (0..1023) + 4 weight converts (1024..4095, n2s
// folded into W1) + rssum zero (block 4096) --------------------------------
__global__ void pre_kernel(const float* __restrict__ x, const float* __restrict__ n1s,
                           const float* __restrict__ n2s, __bf16* __restrict__ xn1,
                           const float* __restrict__ wa, const float* __restrict__ wb,
                           const float* __restrict__ wc, const float* __restrict__ wd,
                           __bf16* __restrict__ da, __bf16* __restrict__ db,
                           __bf16* __restrict__ dc, __bf16* __restrict__ dd,
                           float* __restrict__ rssum) {
    if (blockIdx.x < 1024) {
        int wave = threadIdx.x >> 6, lane = threadIdx.x & 63;
        int tok = blockIdx.x * 4 + wave;
        const float* row = x + (size_t)tok * DMODEL;
        float4 v0 = *(const float4*)&row[lane * 4];
        float4 v1 = *(const float4*)&row[256 + lane * 4];
        float ss = v0.x*v0.x + v0.y*v0.y + v0.z*v0.z + v0.w*v0.w
                 + v1.x*v1.x + v1.y*v1.y + v1.z*v1.z + v1.w*v1.w;
        #pragma unroll
        for (int off = 1; off < 64; off <<= 1) ss += __shfl_xor(ss, off);
        float r = rsqrtf(ss * (1.0f / DMODEL) + 1e-8f);
        __bf16* o = xn1 + (size_t)tok * DMODEL;
        o[lane*4 + 0] = (__bf16)(v0.x * r * n1s[lane*4 + 0]);
        o[lane*4 + 1] = (__bf16)(v0.y * r * n1s[lane*4 + 1]);
        o[lane*4 + 2] = (__bf16)(v0.z * r * n1s[lane*4 + 2]);
        o[lane*4 + 3] = (__bf16)(v0.w * r * n1s[lane*4 + 3]);
        o[256 + lane*4 + 0] = (__bf16)(v1.x * r * n1s[256 + lane*4 + 0]);
        o[256 + lane*4 + 1] = (__bf16)(v1.y * r * n1s[256 + lane*4 + 1]);
        o[256 + lane*4 + 2] = (__bf16)(v1.z * r * n1s[256 + lane*4 + 2]);
        o[256 + lane*4 + 3] = (__bf16)(v1.w * r * n1s[256 + lane*4 + 3]);
    } else if (blockIdx.x < 4096) {
        const int N0 = 1536 * 512, N1 = 512 * 512, N2 = 2048 * 512, N3 = 512 * 2048;
        int i4 = ((blockIdx.x - 1024) * 256 + threadIdx.x) * 4;
        if (i4 < N0) {
            float4 v = *(const float4*)&wa[i4];
            __bf16* d = da + i4;
            d[0] = (__bf16)v.x; d[1] = (__bf16)v.y; d[2] = (__bf16)v.z; d[3] = (__bf16)v.w;
        } else if ((i4 -= N0) < N1) {
            float4 v = *(const float4*)&wb[i4];
            __bf16* d = db + i4;
            d[0] = (__bf16)v.x; d[1] = (__bf16)v.y; d[2] = (__bf16)v.z; d[3] = (__bf16)v.w;
        } else if ((i4 -= N1) < N2) {
            float4 v = *(const float4*)&wc[i4];
            float4 sc = *(const float4*)&n2s[i4 & 511];   // fold n2s into W1
            __bf16* d = dc + i4;
            d[0] = (__bf16)(v.x * sc.x); d[1] = (__bf16)(v.y * sc.y);
            d[2] = (__bf16)(v.z * sc.z); d[3] = (__bf16)(v.w * sc.w);
        } else if ((i4 -= N2) < N3) {
            float4 v = *(const float4*)&wd[i4];
            __bf16* d = dd + i4;
            d[0] = (__bf16)v.x; d[1] = (__bf16)v.y; d[2] = (__bf16)v.z; d[3] = (__bf16)v.w;
        }
    } else {
        // zero rssum[4096]
        float4 z = make_float4(0.f, 0.f, 0.f, 0.f);
        int i = threadIdx.x * 16;
        *(float4*)&rssum[i + 0]  = z;
        *(float4*)&rssum[i + 4]  = z;
        *(float4*)&rssum[i + 8]  = z;
        *(float4*)&rssum[i + 12] = z;
    }
}

// ---------------- GEMM: C[M,N] = A[M,K] @ W[N,K]^T (+ bias), TN=128 --------
// EPI: 4 = qkv split: Q*QSCALE -> qb, K -> kb, V -> vtb (key-permuted pack)
//      5 = fp32 unsafeAtomicAdd into Cf (no bias; split-K via blockIdx.z)
//      8 = x1 = res + C + bias: write Cb=bf16 x1, Cf = x1 + b2x (out preinit),
//          and atomicAdd per-row sum-of-squares into rssum
//      9 = bf16 tanh-gelu(C * rms[row] + bias), rms from rssum (MLP1)
template <int EPI, int TM, int KS = 1>
__global__ __launch_bounds__(256) void gemm_bt(
    const __bf16* __restrict__ A, const __bf16* __restrict__ W,
    const float* __restrict__ bias, const float* __restrict__ res,
    float* __restrict__ Cf, __bf16* __restrict__ Cb,
    __bf16* __restrict__ qb, __bf16* __restrict__ kb, __bf16* __restrict__ vtb,
    const float* __restrict__ b2x, float* __restrict__ rssum,
    int M, int N, int K)
{
    constexpr int RI = TM / 32;
    __shared__ alignas(16) __bf16 As[2][TM * 32];
    __shared__ alignas(16) __bf16 Bs[2][128 * 32];
    const int tid = threadIdx.x;
    const int bm = blockIdx.x * TM;
    const int bn = blockIdx.y * 128;
    const int wave = tid >> 6, lane = tid & 63;
    const int wm = (wave & 1) * (TM / 2), wn = (wave >> 1) * 64;
    const int lrow = lane & 15;
    const int kq = (lane >> 4) * 8;

    f32x4 acc[RI][4] = {};

    const int Kc = K / KS;
    const int kbeg = (KS > 1) ? blockIdx.z * Kc : 0;

    for (int k0 = kbeg; k0 < kbeg + Kc; k0 += 64) {
        __syncthreads();
        #pragma unroll
        for (int i = 0; i < TM / 32; i++) {
            int tt = i * 256 + tid;
            int kh = tt / (TM * 4), rem = tt % (TM * 4);
            int mrow = rem >> 2, c8 = rem & 3;
            gl_lds16(&A[(size_t)(bm + mrow) * K + k0 + kh * 32 + c8 * 8],
                     (__bf16*)As + tt * 8);
        }
        #pragma unroll
        for (int i = 0; i < 4; i++) {
            int tt = i * 256 + tid;
            int kh = tt >> 9, rem = tt & 511;
            int nrow = rem >> 2, c8 = rem & 3;
            gl_lds16(&W[(size_t)(bn + nrow) * K + k0 + kh * 32 + c8 * 8],
                     (__bf16*)Bs + tt * 8);
        }
        __syncthreads();
        #pragma unroll
        for (int kh = 0; kh < 2; kh++) {
            bf16x8 af[RI], bfv[4];
            #pragma unroll
            for (int i = 0; i < RI; i++) af[i] = *(bf16x8*)&As[kh][(wm + i*16 + lrow)*32 + kq];
            #pragma unroll
            for (int j = 0; j < 4; j++) bfv[j] = *(bf16x8*)&Bs[kh][(wn + j*16 + lrow)*32 + kq];
            #pragma unroll
            for (int i = 0; i < RI; i++)
                #pragma unroll
                for (int j = 0; j < 4; j++)
                    acc[i][j] = __builtin_amdgcn_mfma_f32_16x16x32_bf16(af[i], bfv[j], acc[i][j], 0, 0, 0);
        }
    }

    const int crow0 = (lane >> 4) * 4;
    const int ccol = lane & 15;
    const int quad = lane >> 4;

    if (EPI == 4) {
        #pragma unroll
        for (int j = 0; j < 4; j++) {
            const int col = bn + wn + j * 16 + ccol;
            const float bv = bias[col];
            if (col < 512) {
                const int h = col >> 6, d = col & 63;
                #pragma unroll
                for (int i = 0; i < RI; i++) {
                    const int row0 = bm + wm + i * 16 + crow0;
                    const int b = row0 >> 11, s0 = row0 & 2047;
                    #pragma unroll
                    for (int r = 0; r < 4; r++)
                        qb[(((size_t)b*8 + h)*2048 + s0 + r)*64 + d] =
                            (__bf16)((acc[i][j][r] + bv) * QSCALE);
                }
            } else if (col < 1024) {
                const int h = (col - 512) >> 6, d = col & 63;
                #pragma unroll
                for (int i = 0; i < RI; i++) {
                    const int row0 = bm + wm + i * 16 + crow0;
                    const int b = row0 >> 11, s0 = row0 & 2047;
                    #pragma unroll
                    for (int r = 0; r < 4; r++)
                        kb[(((size_t)b*8 + h)*2048 + s0 + r)*64 + d] = (__bf16)(acc[i][j][r] + bv);
                }
            } else {
                const int h = (col - 1024) >> 6, d = col & 63;
                const int tok0 = bm + wm;            // 32-aligned
                const int b = tok0 >> 11, sbase = tok0 & 2047;
                unsigned* vrow = (unsigned*)vtb + (((size_t)b*8 + h)*64 + d) * 1024 + (sbase >> 1);
                #pragma unroll
                for (int ip = 0; ip < RI / 2; ip++) {
                    #pragma unroll
                    for (int r = 0; r < 4; r++) {
                        PkU pk;                      // c' = 2*(g&15) + (g>>4)
                        pk.h[0] = (__bf16)(acc[2*ip][j][r] + bv);
                        pk.h[1] = (__bf16)(acc[2*ip+1][j][r] + bv);
                        vrow[ip * 16 + quad * 4 + r] = pk.u;
                    }
                }
            }
        }
    } else {
        #pragma unroll
        for (int i = 0; i < RI; i++) {
            const int row0 = bm + wm + i * 16 + crow0;
            if (EPI == 9) {
                float rms[4];
                #pragma unroll
                for (int r = 0; r < 4; r++)
                    rms[r] = rsqrtf(rssum[row0 + r] * (1.0f / 512.0f) + 1e-8f);
                #pragma unroll
                for (int j = 0; j < 4; j++) {
                    const int col = bn + wn + j * 16 + ccol;
                    const float bv = bias[col];
                    #pragma unroll
                    for (int r = 0; r < 4; r++) {
                        float v = acc[i][j][r] * rms[r] + bv;
                        // tanh-gelu
                        float u = v * (0.7978845608f + 0.0356774081f * v * v);
                        float t = exp2f(u * 2.8853900818f);
                        Cb[(size_t)(row0 + r) * N + col] = (__bf16)(v - v / (t + 1.0f));
                    }
                }
            } else if (EPI == 8) {
                float ssq[4] = {};
                #pragma unroll
                for (int j = 0; j < 4; j++) {
                    const int col = bn + wn + j * 16 + ccol;
                    const float bv = bias[col], b2v = b2x[col];
                    #pragma unroll
                    for (int r = 0; r < 4; r++) {
                        const size_t idx = (size_t)(row0 + r) * N + col;
                        float v = res[idx] + acc[i][j][r] + bv;
                        Cb[idx] = (__bf16)v;          // x1 bf16
                        Cf[idx] = v + b2v;            // out preinit
                        ssq[r] += v * v;
                    }
                }
                #pragma unroll
                for (int r = 0; r < 4; r++) {
                    #pragma unroll
                    for (int off = 1; off < 16; off <<= 1)
                        ssq[r] += __shfl_xor(ssq[r], off);
                }
                if (ccol == 0) {
                    #pragma unroll
                    for (int r = 0; r < 4; r++)
                        unsafeAtomicAdd(&rssum[row0 + r], ssq[r]);
                }
            } else { // EPI == 5
                #pragma unroll
                for (int j = 0; j < 4; j++) {
                    const int col = bn + wn + j * 16 + ccol;
                    #pragma unroll
                    for (int r = 0; r < 4; r++)
                        unsafeAtomicAdd(&Cf[(size_t)(row0 + r) * N + col], acc[i][j][r]);
                }
            }
        }
    }
}

// ---------------- ALiBi-windowed flash attention ----------------------------
// grid flat 512; qt = id>>4, bh = (id&15) ^ (7*(id>>8)) pairs heads h, 7-h
// per CU. Key tiles limited to |dist| <= 16*(h+1)+16. m=0 softmax, direct
// ctx write.
__global__ __launch_bounds__(256) void attn_kernel(
    const __bf16* __restrict__ qb, const __bf16* __restrict__ kb,
    const __bf16* __restrict__ vtb, __bf16* __restrict__ ctx)
{
    const int id = blockIdx.x;
    const int qt = id >> 4;
    const int bh = (id & 15) ^ (7 * (id >> 8));
    const int h = bh & 7, b = bh >> 3;
    const int tid = threadIdx.x, wave = tid >> 6, lane = tid & 63;
    const int lrow = lane & 15, quad = lane >> 4;

    __shared__ alignas(16) __bf16 Ks[2][2][64 * 32];
    __shared__ alignas(16) __bf16 Vt[2][2][64 * 32];
    __shared__ alignas(16) unsigned Pt4[4][2][16][20];

    const float slope2 = -1.44269504f / (float)(h + 1);
    const int q0 = qt * 64;
    const int D = 16 * (h + 1) + 16;
    const int kt_lo = max(0, q0 - D) >> 6;
    const int kt_hi = min(SEQ - 1, q0 + 63 + D) >> 6;

    bf16x8 qf[2];
    #pragma unroll
    for (int dh = 0; dh < 2; dh++)
        qf[dh] = *(const bf16x8*)&qb[((size_t)bh*2048 + q0 + wave*16 + lrow)*64 + dh*32 + quad*8];

    bf16x8 ones;
    #pragma unroll
    for (int j = 0; j < 8; j++) ones[j] = (__bf16)1.0f;

    f32x4 O[4] = {};
    f32x4 lacc = {};

    auto stage = [&](int kt, int buf) {
        const int kbase = kt * 64;
        #pragma unroll
        for (int i = 0; i < 2; i++) {
            int tt = i * 256 + tid;
            int dh = tt >> 8, key = (tt & 255) >> 2, c8 = (tt & 3) * 8;
            gl_lds16(&kb[((size_t)bh*2048 + kbase + key)*64 + dh*32 + c8],
                     (__bf16*)Ks[buf] + tt * 8);
        }
        #pragma unroll
        for (int i = 0; i < 2; i++) {
            int tt = i * 256 + tid;
            int kh = tt >> 8, d = (tt & 255) >> 2, ck = (tt & 3) * 8;
            gl_lds16(&vtb[((size_t)bh*64 + d)*2048 + kbase + kh*32 + ck],
                     (__bf16*)Vt[buf] + tt * 8);
        }
    };

    stage(kt_lo, 0);

    for (int kt = kt_lo, buf = 0; kt <= kt_hi; kt++, buf ^= 1) {
        __syncthreads();
        if (kt < kt_hi) stage(kt + 1, buf ^ 1);

        bf16x8 kf[4][2];
        #pragma unroll
        for (int j = 0; j < 4; j++)
            #pragma unroll
            for (int dh = 0; dh < 2; dh++)
                kf[j][dh] = *(bf16x8*)&Ks[buf][dh][(j*16 + lrow)*32 + quad*8];

        f32x4 Sc[4] = {};
        #pragma unroll
        for (int dh = 0; dh < 2; dh++)
            #pragma unroll
            for (int j = 0; j < 4; j++)
                Sc[j] = __builtin_amdgcn_mfma_f32_16x16x32_bf16(qf[dh], kf[j][dh], Sc[j], 0, 0, 0);

        const float dbase = (float)(q0 + wave*16 + quad*4 - kt*64 - lrow);
        #pragma unroll
        for (int r = 0; r < 4; r++) {
            const float d0 = dbase + (float)r;
            #pragma unroll
            for (int jp = 0; jp < 2; jp++) {
                float v0 = fmaf(slope2, fabsf(d0 - (float)(jp*32)),      Sc[2*jp  ][r]);
                float v1 = fmaf(slope2, fabsf(d0 - (float)(jp*32 + 16)), Sc[2*jp+1][r]);
                PkU pk;
                pk.h[0] = (__bf16)exp2f(v0);
                pk.h[1] = (__bf16)exp2f(v1);
                Pt4[wave][jp][quad*4 + r][lrow] = pk.u;
            }
        }

        bf16x8 pf[2];
        #pragma unroll
        for (int kh = 0; kh < 2; kh++)
            pf[kh] = *(bf16x8*)&Pt4[wave][kh][lrow][quad*4];

        #pragma unroll
        for (int kh = 0; kh < 2; kh++)
            lacc = __builtin_amdgcn_mfma_f32_16x16x32_bf16(pf[kh], ones, lacc, 0, 0, 0);

        #pragma unroll
        for (int dt = 0; dt < 4; dt++) {
            #pragma unroll
            for (int kh = 0; kh < 2; kh++) {
                bf16x8 vf = *(bf16x8*)&Vt[buf][kh][(dt*16 + lrow)*32 + quad*8];
                O[dt] = __builtin_amdgcn_mfma_f32_16x16x32_bf16(pf[kh], vf, O[dt], 0, 0, 0);
            }
        }
    }

    #pragma unroll
    for (int dt = 0; dt < 4; dt++) {
        #pragma unroll
        for (int r = 0; r < 4; r++) {
            const int q = q0 + wave*16 + quad*4 + r;
            ctx[((size_t)(b * 2048 + q)) * DMODEL + h * 64 + dt*16 + lrow] =
                (__bf16)(O[dt][r] / lacc[r]);
        }
    }
}

// ---------------------------------------------------------------------------
extern "C" void kernel_launch(void* const* d_in, const int* in_sizes, int n_in,
                              void* d_out, int out_size, void* d_ws, size_t ws_size,
                              hipStream_t stream) {
    const float* x    = (const float*)d_in[0];
    const float* n1s  = (const float*)d_in[1];
    const float* n2s  = (const float*)d_in[2];
    const float* wqkv = (const float*)d_in[3];
    const float* bqkv = (const float*)d_in[4];
    const float* wout = (const float*)d_in[5];
    const float* bout = (const float*)d_in[6];
    const float* w1   = (const float*)d_in[7];
    const float* b1   = (const float*)d_in[8];
    const float* w2   = (const float*)d_in[9];
    const float* b2   = (const float*)d_in[10];
    float* out = (float*)d_out;

    char* ws = (char*)d_ws;
    __bf16* xn1     = (__bf16*)ws; ws += (size_t)TOKENS * DMODEL * 2;
    __bf16* qbuf    = (__bf16*)ws; ws += (size_t)TOKENS * DMODEL * 2;
    __bf16* kbuf    = (__bf16*)ws; ws += (size_t)TOKENS * DMODEL * 2;
    __bf16* vtbuf   = (__bf16*)ws; ws += (size_t)TOKENS * DMODEL * 2;
    __bf16* wqkv_b  = (__bf16*)ws; ws += (size_t)1536 * DMODEL * 2;
    __bf16* wout_b  = (__bf16*)ws; ws += (size_t)DMODEL * DMODEL * 2;
    __bf16* w1n_b   = (__bf16*)ws; ws += (size_t)2048 * DMODEL * 2;
    __bf16* w2_b    = (__bf16*)ws; ws += (size_t)DMODEL * 2048 * 2;
    __bf16* ctx     = (__bf16*)ws; ws += (size_t)TOKENS * DMODEL * 2;
    __bf16* x1b     = (__bf16*)ws; ws += (size_t)TOKENS * DMODEL * 2;
    __bf16* hbuf    = (__bf16*)ws; ws += (size_t)TOKENS * 2048 * 2;
    float*  rssum   = (float*)ws;  ws += (size_t)TOKENS * 4;

    // 1) rmsnorm1 + weight converts (n2s folded into W1) + rssum zero
    pre_kernel<<<dim3(4097), 256, 0, stream>>>(x, n1s, n2s, xn1,
        wqkv, wout, w1, w2, wqkv_b, wout_b, w1n_b, w2_b, rssum);

    // 2) qkv GEMM (64x128 tiles, 768 blocks) -> q (scaled), k, v-perm
    gemm_bt<4, 64><<<dim3(TOKENS / 64, 1536 / 128), 256, 0, stream>>>(
        xn1, wqkv_b, bqkv, nullptr, nullptr, nullptr, qbuf, kbuf, vtbuf,
        nullptr, nullptr, TOKENS, 1536, DMODEL);

    // 3) windowed attention -> ctx (512 blocks)
    attn_kernel<<<dim3(512), 256, 0, stream>>>(qbuf, kbuf, vtbuf, ctx);

    // 4) x1 = x + ctx @ Wout^T + bout -> x1b (bf16); out = x1 + b2;
    //    rssum += per-row sum(x1^2)   (32x128 tiles, 512 blocks)
    gemm_bt<8, 32><<<dim3(TOKENS / 32, DMODEL / 128), 256, 0, stream>>>(
        ctx, wout_b, bout, x, out, x1b, nullptr, nullptr, nullptr,
        b2, rssum, TOKENS, DMODEL, DMODEL);

    // 5) h = tanh-gelu(rms[row] * (x1b @ W1n^T) + b1)  (64x128, 1024 blocks)
    gemm_bt<9, 64><<<dim3(TOKENS / 64, 2048 / 128), 256, 0, stream>>>(
        x1b, w1n_b, b1, nullptr, nullptr, hbuf, nullptr, nullptr, nullptr,
        nullptr, rssum, TOKENS, 2048, DMODEL);

    // 6) out += h @ W2^T  (split-K=2 atomics, 1024 blocks)
    gemm_bt<5, 32, 2><<<dim3(TOKENS / 32, DMODEL / 128, 2), 256, 0, stream>>>(
        hbuf, w2_b, nullptr, nullptr, out, nullptr, nullptr, nullptr, nullptr,
        nullptr, nullptr, TOKENS, DMODEL, 2048);
}